// Round 7
// baseline (565.008 us; speedup 1.0000x reference)
//
#include <hip/hip_runtime.h>

#define S_SCALE 30.0f
#define COS_M 0.8775825618903728f
#define SIN_M 0.479425538604203f
#define TH_C (-0.8775825618903728f)
#define MM_C 0.2397127693021015f

#define BD 512
#define DD 512
#define CC 100000
#define NCB 3125            // 100000 / 32 exactly (no tail)

typedef __bf16 bf16x8 __attribute__((ext_vector_type(8)));
typedef __bf16 bf16x2 __attribute__((ext_vector_type(2)));
typedef float  f32x4  __attribute__((ext_vector_type(4)));

#define AS1 __attribute__((address_space(1)))
#define AS3 __attribute__((address_space(3)))

// ---------------- Kernel 1: concat + normalize -> k-tiled bf16 At[16][512][32];
// label-column cosine/phi; zero sums[512]. ----------------
__global__ __launch_bounds__(256) void k_prep(const float* __restrict__ img,
                                              const float* __restrict__ prof,
                                              const float* __restrict__ W,
                                              const int* __restrict__ lab,
                                              __bf16* __restrict__ At,
                                              float* __restrict__ sphi,
                                              float* __restrict__ scos,
                                              float* __restrict__ sums) {
    const int row = blockIdx.x;
    const int t = threadIdx.x;
    const float* src = (row < 256) ? (img + (size_t)row * DD) : (prof + (size_t)(row - 256) * DD);
    float x0 = src[t], x1 = src[t + 256];
    float s = x0 * x0 + x1 * x1;
    for (int o = 1; o < 64; o <<= 1) s += __shfl_xor(s, o);
    __shared__ float ws4[4];
    if ((t & 63) == 0) ws4[t >> 6] = s;
    __syncthreads();
    float r = rsqrtf(ws4[0] + ws4[1] + ws4[2] + ws4[3]);
    __bf16 a0 = (__bf16)(x0 * r), a1 = (__bf16)(x1 * r);
    // k-tiled: (row, d) -> At[(d>>5)*16384 + row*32 + (d&31)]
    At[(size_t)(t >> 5) * (BD * 32) + row * 32 + (t & 31)]         = a0;
    At[(size_t)((t + 256) >> 5) * (BD * 32) + row * 32 + (t & 31)] = a1;

    const int c = lab[row & 255];
    float w0 = (float)(__bf16)W[(size_t)c * DD + t];
    float w1 = (float)(__bf16)W[(size_t)c * DD + t + 256];
    float dot = (float)a0 * w0 + (float)a1 * w1;
    float wsq = w0 * w0 + w1 * w1;
    for (int o = 1; o < 64; o <<= 1) { dot += __shfl_xor(dot, o); wsq += __shfl_xor(wsq, o); }
    __shared__ float sd[4], sw[4];
    if ((t & 63) == 0) { sd[t >> 6] = dot; sw[t >> 6] = wsq; }
    __syncthreads();
    if (t == 0) {
        float D = sd[0] + sd[1] + sd[2] + sd[3];
        float Q = sw[0] + sw[1] + sw[2] + sw[3];
        float cs = D * rsqrtf(Q);
        float sn = sqrtf(fmaxf(0.f, fminf(1.f, 1.f - cs * cs)));
        float phi = cs * COS_M - sn * SIN_M;
        if (!(cs > TH_C)) phi = cs - MM_C;
        sphi[row] = S_SCALE * phi;
        scos[row] = S_SCALE * cs;
        sums[row] = 0.f;
    }
}

// ---------------- Kernel 2: MFMA GEMM, 512 rows x 32 cols / block, 8 waves ----------------
// Wave tile 64r x 32c: acc = 32 AGPR -> ~85 total regs, fits the 128 cap of 4 waves/SIMD
// WITHOUT spill (R4/R6 failure mode). 2 blocks/CU (68.5KB LDS) = 16 waves/CU.
// One barrier per tile at body top; glds A(kt+1) + raw W(kt+2) issued right after it
// so every load is in flight for a full body before the barrier's vmcnt(0) drain.
__global__ __launch_bounds__(512, 4) void k_gemm(const __bf16* __restrict__ At,
                                                 const float* __restrict__ W,
                                                 float* __restrict__ sums) {
    __shared__ __bf16 As[2][BD * 32];   // 2 x 32 KB
    __shared__ __bf16 Bs[2][32 * 32];   // 2 x 2 KB
    __shared__ float  csq[32];

    const int t = threadIdx.x;          // 0..511
    const int cb = blockIdx.x;
    const int wave = t >> 6, lane = t & 63, q = lane >> 4, m16 = lane & 15;

    // B staging: thread t -> col t>>4 (0..31), k-pair (t&15)*2
    const int bcol = t >> 4, kq = t & 15;
    const float* wp = W + (size_t)(cb * 32 + bcol) * DD + kq * 2;

    f32x4 acc[4][2] = {};
    float sq = 0.f;

#define GLDS_TILE(kt, buf)                                                              \
    {                                                                                   \
        const char* gs = (const char*)At + (size_t)(kt) * 32768;                        \
        char* ls = (char*)(&As[buf][0]);                                                \
        _Pragma("unroll")                                                               \
        for (int c4 = 0; c4 < 4; ++c4)                                                  \
            __builtin_amdgcn_global_load_lds(                                           \
                (AS1 void*)(gs + c4 * 8192 + t * 16),                                   \
                (AS3 void*)(ls + c4 * 8192 + wave * 1024 + lane * 16), 16, 0, 0);       \
    }

#define CVT_BS(buf, v)                                                                  \
    {                                                                                   \
        bf16x2 b = { (__bf16)v.x, (__bf16)v.y };                                        \
        float f0 = (float)b[0], f1 = (float)b[1];                                       \
        sq += f0 * f0 + f1 * f1;                                                        \
        *(bf16x2*)(&Bs[buf][bcol * 32 + kq * 2]) = b;                                   \
    }

    // prologue: B(0)->Bs[0], glds A(0), raw B(1)
    {
        float2 b0 = *(const float2*)(wp);
        CVT_BS(0, b0);
        GLDS_TILE(0, 0);
    }
    float2 braw_cur = *(const float2*)(wp + 32);   // tile 1
    float2 braw_nxt;

    #pragma unroll
    for (int kt = 0; kt < 16; ++kt) {
        const int cur = kt & 1;
        __syncthreads();   // drains prev body's glds+raw; As[cur]/Bs[cur] ready

        // issue next-tile loads immediately: one full body in flight before next drain
        if (kt < 15) GLDS_TILE(kt + 1, 1 - cur);
        if (kt < 14) braw_nxt = *(const float2*)(wp + (kt + 2) * 32);

        // compute tile kt
        bf16x8 bfr[2];
        #pragma unroll
        for (int j = 0; j < 2; ++j)
            bfr[j] = *(const bf16x8*)(&Bs[cur][(j * 16 + m16) * 32 + q * 8]);
        #pragma unroll
        for (int i = 0; i < 4; ++i) {
            bf16x8 af = *(const bf16x8*)(&As[cur][(wave * 64 + i * 16 + m16) * 32 + q * 8]);
            acc[i][0] = __builtin_amdgcn_mfma_f32_16x16x32_bf16(af, bfr[0], acc[i][0], 0, 0, 0);
            acc[i][1] = __builtin_amdgcn_mfma_f32_16x16x32_bf16(af, bfr[1], acc[i][1], 0, 0, 0);
        }

        if (kt < 15) {
            CVT_BS(1 - cur, braw_cur);   // B(kt+1), loaded one body ago
            braw_cur = braw_nxt;
        }
    }
#undef GLDS_TILE
#undef CVT_BS

    // per-col sumsq: reduce over the 16 staging threads of each col (lane bits 0..3)
    sq += __shfl_xor(sq, 1);
    sq += __shfl_xor(sq, 2);
    sq += __shfl_xor(sq, 4);
    sq += __shfl_xor(sq, 8);
    if (kq == 0) csq[bcol] = sq;
    __syncthreads();

    // epilogue: cosine scale + exp + per-row reduce + atomicAdd into sums[512]
    float inv[2];
    #pragma unroll
    for (int j = 0; j < 2; ++j) inv[j] = rsqrtf(csq[j * 16 + m16]) * S_SCALE;
    #pragma unroll
    for (int i = 0; i < 4; ++i) {
        #pragma unroll
        for (int r = 0; r < 4; ++r) {
            float e = __expf(acc[i][0][r] * inv[0]) + __expf(acc[i][1][r] * inv[1]);
            e += __shfl_xor(e, 1);
            e += __shfl_xor(e, 2);
            e += __shfl_xor(e, 4);
            e += __shfl_xor(e, 8);
            if (m16 == 0) {
                int row = wave * 64 + i * 16 + q * 4 + r;
                atomicAdd(&sums[row], e);
            }
        }
    }
}

// ---------------- Kernel 3: final logsumexp + label correction + mean ----------------
__global__ __launch_bounds__(256) void k_final(const float* __restrict__ sums,
                                               const float* __restrict__ sphi,
                                               const float* __restrict__ scos,
                                               float* __restrict__ out) {
    const int t = threadIdx.x;
    float acc = 0.f;
    #pragma unroll
    for (int h = 0; h < 2; ++h) {
        int row = t + h * 256;
        float lse = logf(sums[row]);
        float sp = sphi[row], sc = scos[row];
        float corr = log1pf(__expf(sp - lse) - __expf(sc - lse));
        acc += lse + corr - sp;
    }
    for (int o = 1; o < 64; o <<= 1) acc += __shfl_xor(acc, o);
    __shared__ float ws4[4];
    if ((t & 63) == 0) ws4[t >> 6] = acc;
    __syncthreads();
    if (t == 0) out[0] = (ws4[0] + ws4[1] + ws4[2] + ws4[3]) * (1.0f / 512.0f);
}

extern "C" void kernel_launch(void* const* d_in, const int* in_sizes, int n_in,
                              void* d_out, int out_size, void* d_ws, size_t ws_size,
                              hipStream_t stream) {
    const float* img  = (const float*)d_in[0];
    const float* prof = (const float*)d_in[1];
    const float* W    = (const float*)d_in[2];
    const int*   lab  = (const int*)d_in[3];

    char* ws = (char*)d_ws;
    __bf16* At   = (__bf16*)ws;                 // 524288 B (k-tiled)
    float* sphi  = (float*)(ws + 524288);       // 2048 B
    float* scos  = (float*)(ws + 526336);       // 2048 B
    float* sums  = (float*)(ws + 528384);       // 2048 B

    k_prep<<<BD, 256, 0, stream>>>(img, prof, W, lab, At, sphi, scos, sums);
    k_gemm<<<NCB, 512, 0, stream>>>(At, W, sums);
    k_final<<<1, 256, 0, stream>>>(sums, sphi, scos, (float*)d_out);
}